// Round 5
// baseline (335.373 us; speedup 1.0000x reference)
//
#include <hip/hip_runtime.h>

typedef _Float16 f16x8 __attribute__((ext_vector_type(8)));
typedef _Float16 f16x2 __attribute__((ext_vector_type(2)));
typedef float    f32x4 __attribute__((ext_vector_type(4)));
typedef float    f32x16 __attribute__((ext_vector_type(16)));

#define N_CTX 16384
#define N_Q   4096
#define DIM   100
#define THR   4.0f

union PkU   { f16x2 h2; unsigned int u; };
union FragU { unsigned int u[4]; f16x8 v; };

#define MFMA32(a, b, c) __builtin_amdgcn_mfma_f32_32x32x16_f16((a), (b), (c), 0, 0, 0)

// ---------------- fused prep ----------------
// blocks 0..15   : qb rows (q fp16, elem 100 = t_j, rest 0)
// blocks 16..79  : a
// blocks 80..143 : qT transpose (rows 100..127 zeroed)
__global__ void prep_all(const float* __restrict__ q, const float* __restrict__ ctx,
                         const float* __restrict__ ker,
                         unsigned short* __restrict__ qb, unsigned short* __restrict__ qT,
                         float* __restrict__ a) {
    int b = blockIdx.x;
    int tid = threadIdx.x;
    if (b < 16) {
        int j = b * 256 + tid;
        const float* row = q + (size_t)j * DIM;
        float buf[100];
        float acc = 0.f;
        #pragma unroll
        for (int d4 = 0; d4 < 25; ++d4) {
            f32x4 v = *reinterpret_cast<const f32x4*>(row + 4 * d4);
            #pragma unroll
            for (int e = 0; e < 4; ++e) {
                buf[4 * d4 + e] = v[e];
                acc += v[e] * ker[100 + 4 * d4 + e];
            }
        }
        unsigned short* orow = qb + (size_t)j * 128;
        #pragma unroll
        for (int c = 0; c < 16; ++c) {
            f16x8 h;
            #pragma unroll
            for (int e = 0; e < 8; ++e) {
                int d = 8 * c + e;
                float v = (d < DIM) ? buf[d] : (d == DIM ? acc : 0.f);
                h[e] = (_Float16)v;
            }
            *reinterpret_cast<f16x8*>(orow + 8 * c) = h;
        }
    } else if (b < 80) {
        int i = (b - 16) * 256 + tid;
        const float* row = ctx + (size_t)i * DIM;
        float acc = 0.f;
        #pragma unroll
        for (int d4 = 0; d4 < 25; ++d4) {
            f32x4 v = *reinterpret_cast<const f32x4*>(row + 4 * d4);
            acc += v[0] * ker[4 * d4] + v[1] * ker[4 * d4 + 1]
                 + v[2] * ker[4 * d4 + 2] + v[3] * ker[4 * d4 + 3];
        }
        a[i] = acc;
    } else {
        __shared__ _Float16 ldsT[100][64];
        int j0 = (b - 80) * 64;
        int r = tid >> 2, c = tid & 3;
        const float* row = q + (size_t)(j0 + r) * DIM + c * 25;
        #pragma unroll
        for (int k = 0; k < 25; ++k) ldsT[c * 25 + k][r] = (_Float16)row[k];
        __syncthreads();
        for (int idx = tid; idx < 128 * 64; idx += 256) {
            int d = idx >> 6, jj = idx & 63;
            qT[(size_t)d * N_Q + j0 + jj] = (d < DIM) ? *(unsigned short*)&ldsT[d][jj]
                                                      : (unsigned short)0;
        }
    }
}

// ---------------- main fused attention (j-split partials) ----------------
// 1024 blocks x 256 thr. it = bid>>1 (rows [it*32, +32)), js = bid&1.
// Wave w sweeps j in [js*2048 + w*512, +512) by 32. Writes block partials.
__global__ __launch_bounds__(256, 4) void attn_main(
    const unsigned short* __restrict__ qb, const unsigned short* __restrict__ qT,
    const float* __restrict__ ctx, const float* __restrict__ ker,
    _Float16* __restrict__ Ub, float* __restrict__ mb,
    float* __restrict__ lb, float* __restrict__ mtb)
{
    __shared__ _Float16 cbL[32 * 128];
    __shared__ _Float16 smU[4][100][32];
    __shared__ float smM[4][32], smL[4][32], smMt[4][32];

    const int tid  = threadIdx.x;
    const int w    = tid >> 6;
    const int lane = tid & 63;
    const int hi   = lane >> 5;
    const int c31  = lane & 31;
    const int bid  = blockIdx.x;
    const int it   = bid >> 1;
    const int js   = bid & 1;
    const int i0   = it * 32;

    // stage cb tile: fp16(ctx*w3), elem 100 = 1.0 (bias col), XOR-swizzled
    {
        int i  = tid >> 3;              // 0..31
        int d0 = (tid & 7) * 16;        // 0..112
        const float* crow = ctx + (size_t)(i0 + i) * DIM;
        f16x8 v0, v1;
        #pragma unroll
        for (int e = 0; e < 8; ++e) {
            int d = d0 + e;
            v0[e] = (d < DIM) ? (_Float16)(crow[d] * ker[200 + d])
                              : (d == DIM ? (_Float16)1.f : (_Float16)0.f);
        }
        #pragma unroll
        for (int e = 0; e < 8; ++e) {
            int d = d0 + 8 + e;
            v1[e] = (d < DIM) ? (_Float16)(crow[d] * ker[200 + d])
                              : (d == DIM ? (_Float16)1.f : (_Float16)0.f);
        }
        int base = i * 256 + d0 * 2;
        int swz  = (i & 7) << 4;
        *reinterpret_cast<f16x8*>(reinterpret_cast<char*>(cbL) + ((base) ^ swz))      = v0;
        *reinterpret_cast<f16x8*>(reinterpret_cast<char*>(cbL) + ((base + 16) ^ swz)) = v1;
    }
    __syncthreads();

    // persistent cb B-fragments (28 VGPR)
    f16x8 cbF[7];
    {
        int cswz = (c31 & 7) << 4;
        #pragma unroll
        for (int kk = 0; kk < 7; ++kk)
            cbF[kk] = *reinterpret_cast<const f16x8*>(
                reinterpret_cast<const char*>(cbL) + ((c31 * 256 + kk * 32 + hi * 16) ^ cswz));
    }

    f32x16 U0 = {}, U1 = {}, U2 = {}, U3 = {};
    float m = -INFINITY, mtrue = -INFINITY, l = 0.f;

    int jbase = js * 2048 + w * 512;
    const unsigned short* qrow = qb + (size_t)(jbase + c31) * 128 + 8 * hi;
    const unsigned short* vrow = qT + (size_t)c31 * N_Q + jbase + 8 * hi;

    for (int s = 0; s < 16; ++s, qrow += 4096, vrow += 32) {
        // ---- all loads for this step up front ----
        f16x8 aq0 = *reinterpret_cast<const f16x8*>(qrow);
        f16x8 aq1 = *reinterpret_cast<const f16x8*>(qrow + 16);
        f16x8 aq2 = *reinterpret_cast<const f16x8*>(qrow + 32);
        f16x8 aq3 = *reinterpret_cast<const f16x8*>(qrow + 48);
        f16x8 aq4 = *reinterpret_cast<const f16x8*>(qrow + 64);
        f16x8 aq5 = *reinterpret_cast<const f16x8*>(qrow + 80);
        f16x8 aq6 = *reinterpret_cast<const f16x8*>(qrow + 96);
        f16x8 av0 = *reinterpret_cast<const f16x8*>(vrow);
        f16x8 av1 = *reinterpret_cast<const f16x8*>(vrow + 16);
        f16x8 av2 = *reinterpret_cast<const f16x8*>(vrow + 32 * N_Q);
        f16x8 av3 = *reinterpret_cast<const f16x8*>(vrow + 32 * N_Q + 16);
        f16x8 av4 = *reinterpret_cast<const f16x8*>(vrow + 64 * N_Q);
        f16x8 av5 = *reinterpret_cast<const f16x8*>(vrow + 64 * N_Q + 16);
        f16x8 av6 = *reinterpret_cast<const f16x8*>(vrow + 96 * N_Q);
        f16x8 av7 = *reinterpret_cast<const f16x8*>(vrow + 96 * N_Q + 16);

        // ---- QK^T (t folded at k=100) ----
        f32x16 sa = {}, sb = {};
        __builtin_amdgcn_s_setprio(1);
        sa = MFMA32(aq0, cbF[0], sa);
        sb = MFMA32(aq1, cbF[1], sb);
        sa = MFMA32(aq2, cbF[2], sa);
        sb = MFMA32(aq3, cbF[3], sb);
        sa = MFMA32(aq4, cbF[4], sa);
        sb = MFMA32(aq5, cbF[5], sb);
        sa = MFMA32(aq6, cbF[6], sa);
        __builtin_amdgcn_s_setprio(0);

        float sc[16];
        #pragma unroll
        for (int r = 0; r < 16; ++r) sc[r] = sa[r] + sb[r];

        // ---- per-half tile max + defer-max ----
        float t0 = fmaxf(sc[0], sc[1]),  t1 = fmaxf(sc[2], sc[3]);
        float t2 = fmaxf(sc[4], sc[5]),  t3 = fmaxf(sc[6], sc[7]);
        float t4 = fmaxf(sc[8], sc[9]),  t5 = fmaxf(sc[10], sc[11]);
        float t6 = fmaxf(sc[12], sc[13]), t7 = fmaxf(sc[14], sc[15]);
        t0 = fmaxf(t0, t1); t2 = fmaxf(t2, t3); t4 = fmaxf(t4, t5); t6 = fmaxf(t6, t7);
        float tm = fmaxf(fmaxf(t0, t2), fmaxf(t4, t6));
        mtrue = fmaxf(mtrue, tm);

        if (__any(tm > m + THR)) {
            float tmf = fmaxf(tm, __shfl_xor(tm, 32, 64));
            float mn = fmaxf(m, tmf);
            float scale = __expf(m - mn);
            U0 *= scale; U1 *= scale; U2 *= scale; U3 *= scale;
            l *= scale;
            m = mn;
        }

        float ps = 0.f;
        #pragma unroll
        for (int r = 0; r < 16; ++r) { sc[r] = __expf(sc[r] - m); ps += sc[r]; }
        l += ps;

        // ---- P -> PV B-operand ----
        unsigned int pk[8], pr[8];
        #pragma unroll
        for (int h2 = 0; h2 < 8; ++h2) {
            PkU u; u.h2[0] = (_Float16)sc[2 * h2]; u.h2[1] = (_Float16)sc[2 * h2 + 1];
            pk[h2] = u.u;
            pr[h2] = (unsigned int)__shfl_xor((int)pk[h2], 32, 64);
        }
        FragU f0, f1;
        f0.u[0] = hi ? pr[2] : pk[0];
        f0.u[1] = hi ? pr[3] : pk[1];
        f0.u[2] = hi ? pk[2] : pr[0];
        f0.u[3] = hi ? pk[3] : pr[1];
        f1.u[0] = hi ? pr[6] : pk[4];
        f1.u[1] = hi ? pr[7] : pk[5];
        f1.u[2] = hi ? pk[6] : pr[4];
        f1.u[3] = hi ? pk[7] : pr[5];

        // ---- PV ----
        __builtin_amdgcn_s_setprio(1);
        U0 = MFMA32(av0, f0.v, U0);
        U1 = MFMA32(av2, f0.v, U1);
        U2 = MFMA32(av4, f0.v, U2);
        U3 = MFMA32(av6, f0.v, U3);
        U0 = MFMA32(av1, f1.v, U0);
        U1 = MFMA32(av3, f1.v, U1);
        U2 = MFMA32(av5, f1.v, U2);
        U3 = MFMA32(av7, f1.v, U3);
        __builtin_amdgcn_s_setprio(0);
    }

    // cross-half finalize
    l += __shfl_xor(l, 32, 64);
    mtrue = fmaxf(mtrue, __shfl_xor(mtrue, 32, 64));

    // stash per-wave partials
    #pragma unroll
    for (int r = 0; r < 16; ++r) {
        int dl = (r & 3) + 8 * (r >> 2) + 4 * hi;
        smU[w][dl][c31]      = (_Float16)U0[r];
        smU[w][32 + dl][c31] = (_Float16)U1[r];
        smU[w][64 + dl][c31] = (_Float16)U2[r];
        if (96 + dl < DIM) smU[w][96 + dl][c31] = (_Float16)U3[r];
    }
    if (lane < 32) { smM[w][c31] = m; smL[w][c31] = l; smMt[w][c31] = mtrue; }
    __syncthreads();

    // in-block combine over 4 waves -> block partial to gmem
    {
        int i32 = tid & 31;
        int seg = tid >> 5;                  // 0..7
        float M = -INFINITY;
        #pragma unroll
        for (int ww = 0; ww < 4; ++ww) M = fmaxf(M, smM[ww][i32]);
        float ew[4];
        float L = 0.f, Mt = -INFINITY;
        #pragma unroll
        for (int ww = 0; ww < 4; ++ww) {
            ew[ww] = __expf(smM[ww][i32] - M);
            L += smL[ww][i32] * ew[ww];
            Mt = fmaxf(Mt, smMt[ww][i32]);
        }
        if (seg == 0) {
            mb[bid * 32 + i32]  = M;
            lb[bid * 32 + i32]  = L;
            mtb[bid * 32 + i32] = Mt;
        }
        _Float16* ub = Ub + (size_t)bid * 3200;
        for (int d = seg; d < DIM; d += 8) {
            float u = 0.f;
            #pragma unroll
            for (int ww = 0; ww < 4; ++ww) u += (float)smU[ww][d][i32] * ew[ww];
            ub[d * 32 + i32] = (_Float16)u;
        }
    }
}

// ---------------- cross-block combine + epilogue ----------------
// 512 blocks x 256 thr; block = i-tile. Merges the 2 j-split partials,
// writes G cols 0..299 and mfull.
__global__ void combine(const _Float16* __restrict__ Ub, const float* __restrict__ mb,
                        const float* __restrict__ lb, const float* __restrict__ mtb,
                        const float* __restrict__ a, const float* __restrict__ ctx,
                        float* __restrict__ G, float* __restrict__ mfull)
{
    int it = blockIdx.x;
    int tid = threadIdx.x;
    int i32 = tid & 31;
    int seg = tid >> 5;
    int b0 = it * 2, b1 = it * 2 + 1;

    float m0 = mb[b0 * 32 + i32], m1 = mb[b1 * 32 + i32];
    float M  = fmaxf(m0, m1);
    float e0 = __expf(m0 - M), e1 = __expf(m1 - M);
    float L  = lb[b0 * 32 + i32] * e0 + lb[b1 * 32 + i32] * e1;
    int row = it * 32 + i32;
    if (seg == 0) mfull[row] = a[row] + fmaxf(mtb[b0 * 32 + i32], mtb[b1 * 32 + i32]);
    float invL = 1.f / L;
    const _Float16* u0 = Ub + (size_t)b0 * 3200;
    const _Float16* u1 = Ub + (size_t)b1 * 3200;
    for (int d = seg; d < DIM; d += 8) {
        float u = (float)u0[d * 32 + i32] * e0 + (float)u1[d * 32 + i32] * e1;
        float ua = u * invL;
        float cv = ctx[(size_t)row * DIM + d];
        size_t base = (size_t)row * 400;
        G[base + d]       = cv;
        G[base + 100 + d] = ua;
        G[base + 200 + d] = ua * cv;
    }
}

// ---------------- b-softmax + h ----------------
__global__ void kernel_h(const float* __restrict__ mfull, const float* __restrict__ ctx,
                         float* __restrict__ hp) {
    __shared__ float sm[256];
    int t = threadIdx.x;
    float v = -INFINITY;
    for (int i = t; i < N_CTX; i += 256) v = fmaxf(v, mfull[i]);
    sm[t] = v; __syncthreads();
    for (int s = 128; s > 0; s >>= 1) { if (t < s) sm[t] = fmaxf(sm[t], sm[t + s]); __syncthreads(); }
    float M = sm[0];
    __syncthreads();
    float z = 0.f;
    for (int i = t; i < N_CTX; i += 256) z += __expf(mfull[i] - M);
    sm[t] = z; __syncthreads();
    for (int s = 128; s > 0; s >>= 1) { if (t < s) sm[t] += sm[t + s]; __syncthreads(); }
    float Z = sm[0];
    if (t < DIM) {
        int i0 = blockIdx.x * 64;
        float acc = 0.f;
        for (int r = 0; r < 64; ++r)
            acc += __expf(mfull[i0 + r] - M) * ctx[(size_t)(i0 + r) * DIM + t];
        hp[t * 256 + blockIdx.x] = acc / Z;
    }
}

__global__ void kernel_hred(const float* __restrict__ hp, float* __restrict__ h) {
    __shared__ float sm[4][128];
    int t = threadIdx.x;
    int d = t & 127, rep = t >> 7;
    float s = 0.f;
    if (d < DIM) for (int b = 0; b < 64; ++b) s += hp[d * 256 + rep * 64 + b];
    sm[rep][d] = s;
    __syncthreads();
    if (rep == 0 && d < DIM) h[d] = sm[0][d] + sm[1][d] + sm[2][d] + sm[3][d];
}

__global__ void kernel_g4(const float* __restrict__ ctx, const float* __restrict__ h,
                          float* __restrict__ G) {
    int idx = blockIdx.x * 256 + threadIdx.x;
    if (idx >= N_CTX * DIM) return;
    int i = idx / DIM;
    int d = idx - i * DIM;
    G[(size_t)i * 400 + 300 + d] = ctx[idx] * h[d];
}

// ---------------- launcher ----------------
extern "C" void kernel_launch(void* const* d_in, const int* in_sizes, int n_in,
                              void* d_out, int out_size, void* d_ws, size_t ws_size,
                              hipStream_t stream) {
    const float* ctx = (const float*)d_in[0];
    const float* q   = (const float*)d_in[1];
    const float* ker = (const float*)d_in[2];
    float* G = (float*)d_out;

    char* ws = (char*)d_ws;
    unsigned short* qb    = (unsigned short*)(ws);                 // 1,048,576
    unsigned short* qT    = (unsigned short*)(ws + 1048576);       // 1,048,576
    float*          a     = (float*)(ws + 2097152);                // 65,536
    float*          mfull = (float*)(ws + 2162688);                // 65,536
    float*          hp    = (float*)(ws + 2228224);                // 102,400
    float*          h     = (float*)(ws + 2330624);                // 512 (pad)
    _Float16*       Ub    = (_Float16*)(ws + 2331136);             // 1024*3200*2 = 6,553,600
    float*          mb    = (float*)(ws + 8884736);                // 131,072
    float*          lb    = (float*)(ws + 9015808);                // 131,072
    float*          mtb   = (float*)(ws + 9146880);                // 131,072 -> 9,277,952 total

    prep_all<<<dim3(144), dim3(256), 0, stream>>>(q, ctx, ker, qb, qT, a);
    attn_main<<<dim3(1024), dim3(256), 0, stream>>>(qb, qT, ctx, ker, Ub, mb, lb, mtb);
    combine<<<dim3(512), dim3(256), 0, stream>>>(Ub, mb, lb, mtb, a, ctx, G, mfull);
    kernel_h<<<dim3(256), dim3(256), 0, stream>>>(mfull, ctx, hp);
    kernel_hred<<<dim3(1), dim3(512), 0, stream>>>(hp, h);
    kernel_g4<<<dim3(6400), dim3(256), 0, stream>>>(ctx, h, G);
}

// Round 6
// 143.405 us; speedup vs baseline: 2.3386x; 2.3386x over previous
//
#include <hip/hip_runtime.h>

typedef _Float16 f16x8 __attribute__((ext_vector_type(8)));
typedef _Float16 f16x2 __attribute__((ext_vector_type(2)));
typedef float    f32x4 __attribute__((ext_vector_type(4)));
typedef float    f32x16 __attribute__((ext_vector_type(16)));
typedef unsigned int u32;

#define N_CTX 16384
#define N_Q   4096
#define DIM   100
#define THR   4.0f

union PkU   { f16x2 h2; unsigned int u; };
union FragU { unsigned int u[4]; f16x8 v; };

#define MFMA32(a, b, c) __builtin_amdgcn_mfma_f32_32x32x16_f16((a), (b), (c), 0, 0, 0)
#define GLOAD_LDS(g, l) __builtin_amdgcn_global_load_lds( \
    (const __attribute__((address_space(1))) u32*)(const void*)(g), \
    (__attribute__((address_space(3))) u32*)(void*)(l), 16, 0, 0)

// ---------------- fused prep ----------------
// blocks 0..15   : qb rows, 256B each, chunk-swizzled: chunk c of row j at
//                  byte (c*16)^((j&7)<<4). d=100 holds t_j, d>100 zero.
// blocks 16..79  : a[i] = c_i . w1
// blocks 80..143 : qT [128 d][4096 j] fp16, row d=100 = ones (l-column),
//                  rows 101..127 zero; within each 128B block chunk c8 at
//                  byte (c8*16)^((d&7)<<4).
__global__ void prep_all(const float* __restrict__ q, const float* __restrict__ ctx,
                         const float* __restrict__ ker,
                         unsigned short* __restrict__ qb, unsigned short* __restrict__ qT,
                         float* __restrict__ a) {
    int b = blockIdx.x;
    int tid = threadIdx.x;
    if (b < 16) {
        int j = b * 256 + tid;
        const float* row = q + (size_t)j * DIM;
        float buf[100];
        float acc = 0.f;
        #pragma unroll
        for (int d4 = 0; d4 < 25; ++d4) {
            #pragma unroll
            for (int e = 0; e < 4; ++e) {
                float v = row[4 * d4 + e];
                buf[4 * d4 + e] = v;
                acc += v * ker[100 + 4 * d4 + e];
            }
        }
        char* orow = (char*)qb + (size_t)j * 256;
        #pragma unroll
        for (int c = 0; c < 16; ++c) {
            f16x8 h;
            #pragma unroll
            for (int e = 0; e < 8; ++e) {
                int d = 8 * c + e;
                float v = (d < DIM) ? buf[d] : (d == DIM ? acc : 0.f);
                h[e] = (_Float16)v;
            }
            *reinterpret_cast<f16x8*>(orow + ((c * 16) ^ ((j & 7) << 4))) = h;
        }
    } else if (b < 80) {
        int i = (b - 16) * 256 + tid;
        const float* row = ctx + (size_t)i * DIM;
        float acc = 0.f;
        #pragma unroll
        for (int d = 0; d < DIM; ++d) acc += row[d] * ker[d];
        a[i] = acc;
    } else {
        __shared__ _Float16 ldsT[100][64];
        int j0 = (b - 80) * 64;
        int r = tid >> 2, c = tid & 3;
        const float* row = q + (size_t)(j0 + r) * DIM + c * 25;
        #pragma unroll
        for (int k = 0; k < 25; ++k) ldsT[c * 25 + k][r] = (_Float16)row[k];
        __syncthreads();
        for (int idx = tid; idx < 1024; idx += 256) {
            int d = idx >> 3, c8 = idx & 7;
            f16x8 v;
            #pragma unroll
            for (int e = 0; e < 8; ++e) {
                int jj = c8 * 8 + e;
                v[e] = (d < DIM) ? ldsT[d][jj]
                                 : (d == DIM ? (_Float16)1.f : (_Float16)0.f);
            }
            char* dst = (char*)qT + (size_t)d * 8192 + (size_t)j0 * 2
                        + ((c8 * 16) ^ ((d & 7) << 4));
            *reinterpret_cast<f16x8*>(dst) = v;
        }
    }
}

// ---------------- main fused attention ----------------
// grid (JS, 128). Block = 4 waves x 32 i = 128 i-rows, j-window = 4096/JS.
// Per 64-j round: DMA-stage qb-tile (16KB) + qT-tile (16KB) into LDS,
// then 2 substeps of 32 j. Waves split i; j-stream shared via LDS.
__global__ __launch_bounds__(256, 3) void attn_main(
    const unsigned short* __restrict__ qb, const unsigned short* __restrict__ qT,
    const float* __restrict__ ctx, const float* __restrict__ ker,
    _Float16* __restrict__ Ub, float* __restrict__ mb,
    float* __restrict__ lb, float* __restrict__ mtb)
{
    __shared__ __align__(16) char stage[32768];
    char* qbL = stage;            // [64 rows][256B], swizzled rows
    char* qTL = stage + 16384;    // [128 rows][128B], swizzled rows

    const int tid  = threadIdx.x;
    const int w    = tid >> 6;
    const int lane = tid & 63;
    const int hi   = lane >> 5;
    const int c31  = lane & 31;
    const int JS   = gridDim.x;
    const int js   = blockIdx.x;
    const int it   = blockIdx.y;
    const int rounds = 64 / JS;           // 64-j rounds per block
    const int iw0  = it * 128 + w * 32;   // this wave's i-tile base

    // persistent cb B-fragments: lane holds cb[iw0+c31][kk*16+8hi+e]
    f16x8 cbF[7];
    {
        const float* crow = ctx + (size_t)(iw0 + c31) * DIM;
        #pragma unroll
        for (int kk = 0; kk < 7; ++kk) {
            f16x8 f;
            #pragma unroll
            for (int e = 0; e < 8; ++e) {
                int d = kk * 16 + 8 * hi + e;
                float v = (d < DIM) ? crow[d] * ker[200 + d] : (d == DIM ? 1.f : 0.f);
                f[e] = (_Float16)v;
            }
            cbF[kk] = f;
        }
    }

    f32x16 U0 = {}, U1 = {}, U2 = {}, U3 = {};   // U^T d-tiles; U3 row4 = l
    float m = -INFINITY, mtrue = -INFINITY;

    const int rswz = (c31 & 7) << 4;
    const int jwin0 = js * (rounds * 64);

    for (int r = 0; r < rounds; ++r) {
        int jbase = jwin0 + r * 64;
        __syncthreads();                       // prior reads done
        {
            int w4 = w * 4;
            #pragma unroll
            for (int k = 0; k < 4; ++k) {      // qb tile: 64 rows x 256B
                int slot = (w4 + k) * 64 + lane;
                const char* src = (const char*)qb + (size_t)(jbase + (slot >> 4)) * 256
                                  + (slot & 15) * 16;
                GLOAD_LDS(src, qbL + (w4 + k) * 1024);
            }
            #pragma unroll
            for (int k = 0; k < 4; ++k) {      // qT tile: 128 rows x 128B
                int slot = (w4 + k) * 64 + lane;
                const char* src = (const char*)qT + (size_t)(slot >> 3) * 8192
                                  + (size_t)jbase * 2 + (slot & 7) * 16;
                GLOAD_LDS(src, qTL + (w4 + k) * 1024);
            }
        }
        __syncthreads();                       // DMA drained (vmcnt0 + barrier)

        #pragma unroll
        for (int sub = 0; sub < 2; ++sub) {
            // ---- aq frags from LDS ----
            const char* qrow = qbL + (sub * 32 + c31) * 256;
            f16x8 aq[7];
            #pragma unroll
            for (int kk = 0; kk < 7; ++kk)
                aq[kk] = *reinterpret_cast<const f16x8*>(qrow + ((kk * 32 + 16 * hi) ^ rswz));

            // ---- QK^T (t folded at k=100) ----
            f32x16 sa = {}, sb = {};
            __builtin_amdgcn_s_setprio(1);
            sa = MFMA32(aq[0], cbF[0], sa);
            sb = MFMA32(aq[1], cbF[1], sb);
            sa = MFMA32(aq[2], cbF[2], sa);
            sb = MFMA32(aq[3], cbF[3], sb);
            sa = MFMA32(aq[4], cbF[4], sa);
            sb = MFMA32(aq[5], cbF[5], sb);
            sa = MFMA32(aq[6], cbF[6], sa);
            __builtin_amdgcn_s_setprio(0);

            float sc[16];
            #pragma unroll
            for (int q16 = 0; q16 < 16; ++q16) sc[q16] = sa[q16] + sb[q16];

            // ---- per-half tile max + defer-max ----
            float t0 = fmaxf(sc[0], sc[1]),  t1 = fmaxf(sc[2], sc[3]);
            float t2 = fmaxf(sc[4], sc[5]),  t3 = fmaxf(sc[6], sc[7]);
            float t4 = fmaxf(sc[8], sc[9]),  t5 = fmaxf(sc[10], sc[11]);
            float t6 = fmaxf(sc[12], sc[13]), t7 = fmaxf(sc[14], sc[15]);
            t0 = fmaxf(t0, t1); t2 = fmaxf(t2, t3);
            t4 = fmaxf(t4, t5); t6 = fmaxf(t6, t7);
            float tm = fmaxf(fmaxf(t0, t2), fmaxf(t4, t6));
            mtrue = fmaxf(mtrue, tm);

            if (__any(tm > m + THR)) {
                float tmf = fmaxf(tm, __shfl_xor(tm, 32, 64));
                float mn = fmaxf(m, tmf);
                float scale = __expf(m - mn);
                U0 *= scale; U1 *= scale; U2 *= scale; U3 *= scale;
                m = mn;
            }

            #pragma unroll
            for (int q16 = 0; q16 < 16; ++q16) sc[q16] = __expf(sc[q16] - m);

            // ---- P -> PV B-operand ----
            unsigned int pk[8], pr[8];
            #pragma unroll
            for (int h2 = 0; h2 < 8; ++h2) {
                PkU u; u.h2[0] = (_Float16)sc[2 * h2]; u.h2[1] = (_Float16)sc[2 * h2 + 1];
                pk[h2] = u.u;
                pr[h2] = (unsigned int)__shfl_xor((int)pk[h2], 32, 64);
            }
            FragU f0, f1;
            f0.u[0] = hi ? pr[2] : pk[0];
            f0.u[1] = hi ? pr[3] : pk[1];
            f0.u[2] = hi ? pk[2] : pr[0];
            f0.u[3] = hi ? pk[3] : pr[1];
            f1.u[0] = hi ? pr[6] : pk[4];
            f1.u[1] = hi ? pr[7] : pk[5];
            f1.u[2] = hi ? pk[6] : pr[4];
            f1.u[3] = hi ? pk[7] : pr[5];

            // ---- PV: av frags from LDS (V^T rows = qT rows) ----
            const int jb2 = sub * 64;          // byte offset within qTL row
            __builtin_amdgcn_s_setprio(1);
            {
                const char* vr = qTL + (size_t)c31 * 128;
                f16x8 a0 = *reinterpret_cast<const f16x8*>(vr + ((jb2 + 16 * hi) ^ rswz));
                f16x8 a1 = *reinterpret_cast<const f16x8*>(vr + ((jb2 + 32 + 16 * hi) ^ rswz));
                U0 = MFMA32(a0, f0.v, U0);
                U0 = MFMA32(a1, f1.v, U0);
            }
            {
                const char* vr = qTL + (size_t)(32 + c31) * 128;
                f16x8 a0 = *reinterpret_cast<const f16x8*>(vr + ((jb2 + 16 * hi) ^ rswz));
                f16x8 a1 = *reinterpret_cast<const f16x8*>(vr + ((jb2 + 32 + 16 * hi) ^ rswz));
                U1 = MFMA32(a0, f0.v, U1);
                U1 = MFMA32(a1, f1.v, U1);
            }
            {
                const char* vr = qTL + (size_t)(64 + c31) * 128;
                f16x8 a0 = *reinterpret_cast<const f16x8*>(vr + ((jb2 + 16 * hi) ^ rswz));
                f16x8 a1 = *reinterpret_cast<const f16x8*>(vr + ((jb2 + 32 + 16 * hi) ^ rswz));
                U2 = MFMA32(a0, f0.v, U2);
                U2 = MFMA32(a1, f1.v, U2);
            }
            {
                const char* vr = qTL + (size_t)(96 + c31) * 128;
                f16x8 a0 = *reinterpret_cast<const f16x8*>(vr + ((jb2 + 16 * hi) ^ rswz));
                f16x8 a1 = *reinterpret_cast<const f16x8*>(vr + ((jb2 + 32 + 16 * hi) ^ rswz));
                U3 = MFMA32(a0, f0.v, U3);
                U3 = MFMA32(a1, f1.v, U3);
            }
            __builtin_amdgcn_s_setprio(0);
        }
    }

    // ---- epilogue: per-wave partials straight to gmem ----
    mtrue = fmaxf(mtrue, __shfl_xor(mtrue, 32, 64));
    float ltmp = __shfl_xor(U3[0], 32, 64);     // U3 reg0/hi=1 holds l (d=100 row)
    float lfull = hi ? U3[0] : ltmp;

    int irow = iw0 + c31;
    if (hi == 0) {
        mb [(size_t)js * N_CTX + irow] = m;
        lb [(size_t)js * N_CTX + irow] = lfull;
        mtb[(size_t)js * N_CTX + irow] = mtrue;
    }
    _Float16* ub = Ub + (((size_t)js * 128 + it) * DIM) * 128 + w * 32 + c31;
    #pragma unroll
    for (int r = 0; r < 16; ++r) {
        int dl = (r & 3) + 8 * (r >> 2) + 4 * hi;
        ub[(size_t)dl * 128]        = (_Float16)U0[r];
        ub[(size_t)(32 + dl) * 128] = (_Float16)U1[r];
        ub[(size_t)(64 + dl) * 128] = (_Float16)U2[r];
        if (96 + dl < DIM) ub[(size_t)(96 + dl) * 128] = (_Float16)U3[r];
    }
}

// ---------------- cross-split combine + epilogue ----------------
template<int JS>
__global__ void combine(const _Float16* __restrict__ Ub, const float* __restrict__ mb,
                        const float* __restrict__ lb, const float* __restrict__ mtb,
                        const float* __restrict__ a, const float* __restrict__ ctx,
                        float* __restrict__ G, float* __restrict__ mfull)
{
    int tid = threadIdx.x;
    int i32 = tid & 31, seg = tid >> 5;
    int row = blockIdx.x * 32 + i32;
    int iblk = row >> 7, il = row & 127;

    float mw[JS];
    float M = -INFINITY;
    #pragma unroll
    for (int js = 0; js < JS; ++js) {
        mw[js] = mb[(size_t)js * N_CTX + row];
        M = fmaxf(M, mw[js]);
    }
    float ew[JS];
    float L = 0.f, Mt = -INFINITY;
    #pragma unroll
    for (int js = 0; js < JS; ++js) {
        ew[js] = __expf(mw[js] - M);
        L += lb[(size_t)js * N_CTX + row] * ew[js];
        Mt = fmaxf(Mt, mtb[(size_t)js * N_CTX + row]);
    }
    if (seg == 0) mfull[row] = a[row] + Mt;
    float invL = 1.f / L;
    for (int d = seg; d < DIM; d += 8) {
        float u = 0.f;
        #pragma unroll
        for (int js = 0; js < JS; ++js)
            u += (float)Ub[(((size_t)js * 128 + iblk) * DIM + d) * 128 + il] * ew[js];
        float ua = u * invL;
        float cv = ctx[(size_t)row * DIM + d];
        size_t base = (size_t)row * 400;
        G[base + d]       = cv;
        G[base + 100 + d] = ua;
        G[base + 200 + d] = ua * cv;
    }
}

// ---------------- b-softmax + h ----------------
__global__ void kernel_h(const float* __restrict__ mfull, const float* __restrict__ ctx,
                         float* __restrict__ hp) {
    __shared__ float sm[256];
    int t = threadIdx.x;
    float v = -INFINITY;
    for (int i = t; i < N_CTX; i += 256) v = fmaxf(v, mfull[i]);
    sm[t] = v; __syncthreads();
    for (int s = 128; s > 0; s >>= 1) { if (t < s) sm[t] = fmaxf(sm[t], sm[t + s]); __syncthreads(); }
    float M = sm[0];
    __syncthreads();
    float z = 0.f;
    for (int i = t; i < N_CTX; i += 256) z += __expf(mfull[i] - M);
    sm[t] = z; __syncthreads();
    for (int s = 128; s > 0; s >>= 1) { if (t < s) sm[t] += sm[t + s]; __syncthreads(); }
    float Z = sm[0];
    if (t < DIM) {
        int i0 = blockIdx.x * 64;
        float acc = 0.f;
        for (int r = 0; r < 64; ++r)
            acc += __expf(mfull[i0 + r] - M) * ctx[(size_t)(i0 + r) * DIM + t];
        hp[t * 256 + blockIdx.x] = acc / Z;
    }
}

__global__ void kernel_hred(const float* __restrict__ hp, float* __restrict__ h) {
    __shared__ float sm[4][128];
    int t = threadIdx.x;
    int d = t & 127, rep = t >> 7;
    float s = 0.f;
    if (d < DIM) for (int b = 0; b < 64; ++b) s += hp[d * 256 + rep * 64 + b];
    sm[rep][d] = s;
    __syncthreads();
    if (rep == 0 && d < DIM) h[d] = sm[0][d] + sm[1][d] + sm[2][d] + sm[3][d];
}

__global__ void kernel_g4(const float* __restrict__ ctx, const float* __restrict__ h,
                          float* __restrict__ G) {
    int idx = blockIdx.x * 256 + threadIdx.x;
    if (idx >= N_CTX * DIM) return;
    int i = idx / DIM;
    int d = idx - i * DIM;
    G[(size_t)i * 400 + 300 + d] = ctx[idx] * h[d];
}

// ---------------- launcher ----------------
extern "C" void kernel_launch(void* const* d_in, const int* in_sizes, int n_in,
                              void* d_out, int out_size, void* d_ws, size_t ws_size,
                              hipStream_t stream) {
    const float* ctx = (const float*)d_in[0];
    const float* q   = (const float*)d_in[1];
    const float* ker = (const float*)d_in[2];
    float* G = (float*)d_out;

    char* ws = (char*)d_ws;
    unsigned short* qb    = (unsigned short*)(ws);                 // 1,048,576
    unsigned short* qT    = (unsigned short*)(ws + 1048576);       // 1,048,576
    float*          a     = (float*)(ws + 2097152);                // 65,536
    float*          mfull = (float*)(ws + 2162688);                // 65,536
    float*          hp    = (float*)(ws + 2228224);                // 102,400
    float*          h     = (float*)(ws + 2330624);                // 512

    const size_t fixed = 2331136;
    // per-JS: Ub = JS*128*100*128*2 ; mb/lb/mtb = JS*65536 each
    int JS = 8;
    if (fixed + 8ull * 3473408ull > ws_size) JS = 4;
    if (fixed + 4ull * 3473408ull > ws_size) JS = 2;

    _Float16* Ub  = (_Float16*)(ws + fixed);
    size_t ubB    = (size_t)JS * 3276800ull;
    float*    mb  = (float*)(ws + fixed + ubB);
    float*    lb  = (float*)(ws + fixed + ubB + (size_t)JS * 65536ull);
    float*    mtb = (float*)(ws + fixed + ubB + (size_t)JS * 131072ull);

    prep_all<<<dim3(144), dim3(256), 0, stream>>>(q, ctx, ker, qb, qT, a);
    attn_main<<<dim3(JS, 128), dim3(256), 0, stream>>>(qb, qT, ctx, ker, Ub, mb, lb, mtb);
    if (JS == 8)
        combine<8><<<dim3(512), dim3(256), 0, stream>>>(Ub, mb, lb, mtb, a, ctx, G, mfull);
    else if (JS == 4)
        combine<4><<<dim3(512), dim3(256), 0, stream>>>(Ub, mb, lb, mtb, a, ctx, G, mfull);
    else
        combine<2><<<dim3(512), dim3(256), 0, stream>>>(Ub, mb, lb, mtb, a, ctx, G, mfull);
    kernel_h<<<dim3(256), dim3(256), 0, stream>>>(mfull, ctx, hp);
    kernel_hred<<<dim3(1), dim3(512), 0, stream>>>(hp, h);
    kernel_g4<<<dim3(6400), dim3(256), 0, stream>>>(ctx, h, G);
}

// Round 7
// 111.597 us; speedup vs baseline: 3.0052x; 1.2850x over previous
//
#include <hip/hip_runtime.h>

typedef _Float16 f16x8 __attribute__((ext_vector_type(8)));
typedef _Float16 f16x2 __attribute__((ext_vector_type(2)));
typedef float    f32x4 __attribute__((ext_vector_type(4)));
typedef float    f32x16 __attribute__((ext_vector_type(16)));
typedef unsigned int u32;

#define N_CTX 16384
#define N_Q   4096
#define DIM   100
#define THR   4.0f

union PkU   { f16x2 h2; unsigned int u; };
union FragU { unsigned int u[4]; f16x8 v; };

#define MFMA32(a, b, c) __builtin_amdgcn_mfma_f32_32x32x16_f16((a), (b), (c), 0, 0, 0)
#define GLOAD_LDS(g, l) __builtin_amdgcn_global_load_lds( \
    (const __attribute__((address_space(1))) u32*)(const void*)(g), \
    (__attribute__((address_space(3))) u32*)(void*)(l), 16, 0, 0)

// ---------------- fused prep ----------------
// qbS: per 32-j block an 8KB image; element (j,d) at byte
//      (d>>3)*512 + (j&31)*16 + (d&7)*2.  d=100 -> t_j, d>100 -> 0.
// cbH: [16384][128] fp16 rows: d<100 -> ctx*w3, d==100 -> 1.0, else 0.
// qTS: per 32-j block an 8KB image; element (d, jl) at byte
//      (d>>5)*2048 + (jl>>3)*512 + (d&31)*16 + (jl&7)*2. d=100 row = ones.
// blocks 0..15 qbS+t | 16..79 a | 80..143 cbH | 144..207 qTS
__global__ void prep_all(const float* __restrict__ q, const float* __restrict__ ctx,
                         const float* __restrict__ ker,
                         unsigned short* __restrict__ qbS, unsigned short* __restrict__ qTS,
                         unsigned short* __restrict__ cbH, float* __restrict__ a) {
    int b = blockIdx.x;
    int tid = threadIdx.x;
    if (b < 16) {
        int j = b * 256 + tid;
        const float* row = q + (size_t)j * DIM;
        float buf[100];
        float acc = 0.f;
        #pragma unroll
        for (int d4 = 0; d4 < 25; ++d4) {
            #pragma unroll
            for (int e = 0; e < 4; ++e) {
                float v = row[4 * d4 + e];
                buf[4 * d4 + e] = v;
                acc += v * ker[100 + 4 * d4 + e];
            }
        }
        char* img = (char*)qbS + (size_t)(j >> 5) * 8192 + (j & 31) * 16;
        #pragma unroll
        for (int o = 0; o < 16; ++o) {
            f16x8 h;
            #pragma unroll
            for (int e = 0; e < 8; ++e) {
                int d = 8 * o + e;
                float v = (d < DIM) ? buf[d] : (d == DIM ? acc : 0.f);
                h[e] = (_Float16)v;
            }
            *reinterpret_cast<f16x8*>(img + o * 512) = h;
        }
    } else if (b < 80) {
        int i = (b - 16) * 256 + tid;
        const float* row = ctx + (size_t)i * DIM;
        float acc = 0.f;
        #pragma unroll
        for (int d = 0; d < DIM; ++d) acc += row[d] * ker[d];
        a[i] = acc;
    } else if (b < 144) {
        int i = (b - 80) * 256 + tid;
        const float* row = ctx + (size_t)i * DIM;
        unsigned short* orow = cbH + (size_t)i * 128;
        #pragma unroll
        for (int c = 0; c < 16; ++c) {
            f16x8 h;
            #pragma unroll
            for (int e = 0; e < 8; ++e) {
                int d = 8 * c + e;
                float v = (d < DIM) ? row[d] * ker[200 + d] : (d == DIM ? 1.f : 0.f);
                h[e] = (_Float16)v;
            }
            *reinterpret_cast<f16x8*>(orow + 8 * c) = h;
        }
    } else {
        __shared__ _Float16 ldsT[100][64];
        int j0 = (b - 144) * 64;
        int r = tid >> 2, c = tid & 3;
        const float* row = q + (size_t)(j0 + r) * DIM + c * 25;
        #pragma unroll
        for (int k = 0; k < 25; ++k) ldsT[c * 25 + k][r] = (_Float16)row[k];
        __syncthreads();
        #pragma unroll
        for (int k = 0; k < 4; ++k) {
            int ci = tid + k * 256;              // 1024 chunks = 2 images
            int jb = ci >> 9;
            int rem = ci & 511;
            int dt = rem >> 7, rem2 = rem & 127;
            int o = rem2 >> 5, rr = rem2 & 31;
            int d = dt * 32 + rr;
            f16x8 v;
            #pragma unroll
            for (int e = 0; e < 8; ++e) {
                int jl = jb * 32 + 8 * o + e;
                v[e] = (d < DIM) ? ldsT[d][jl] : (d == DIM ? (_Float16)1.f : (_Float16)0.f);
            }
            char* dst = (char*)qTS + (size_t)((j0 >> 5) + jb) * 8192
                        + dt * 2048 + o * 512 + rr * 16;
            *reinterpret_cast<f16x8*>(dst) = v;
        }
    }
}

// ---------------- main fused attention ----------------
// grid (128, JS). Block = 4 waves x 32 i. Wave sweeps R = 128/JS rounds of
// 32 j, double-buffered LDS staging (stage next THEN compute current).
// All ds_reads are base + lane*16 (conflict-free).
__global__ __launch_bounds__(256, 3) void attn_main(
    const unsigned short* __restrict__ qbS, const unsigned short* __restrict__ qTS,
    const unsigned short* __restrict__ cbH,
    _Float16* __restrict__ Ub, float* __restrict__ mb,
    float* __restrict__ lb, float* __restrict__ mtb)
{
    __shared__ __align__(16) char stageMem[2][16384];

    const int tid  = threadIdx.x;
    const int w    = tid >> 6;
    const int lane = tid & 63;
    const int hi   = lane >> 5;
    const int c31  = lane & 31;
    const int it   = blockIdx.x;
    const int js   = blockIdx.y;
    const int JS   = gridDim.y;
    const int R    = (N_Q / 32) / JS;
    const int iw0  = it * 128 + w * 32;

    // persistent cb B-fragments from cbH (7 x 16B loads)
    f16x8 cbF[7];
    {
        const unsigned short* crow = cbH + (size_t)(iw0 + c31) * 128 + 8 * hi;
        #pragma unroll
        for (int kk = 0; kk < 7; ++kk)
            cbF[kk] = *reinterpret_cast<const f16x8*>(crow + kk * 16);
    }

    f32x16 U0 = {}, U1 = {}, U2 = {}, U3 = {};
    float m = -INFINITY, mtrue = -INFINITY;

    const int bb0 = js * R;
    const int seg = w * 2;
    const int l16 = lane * 16;

    auto stage_fn = [&](int buf, int bb) {
        const char* gq = (const char*)qbS + (size_t)bb * 8192;
        const char* gt = (const char*)qTS + (size_t)bb * 8192;
        char* lq = stageMem[buf];
        #pragma unroll
        for (int k = 0; k < 2; ++k)
            GLOAD_LDS(gq + (seg + k) * 1024 + l16, lq + (seg + k) * 1024);
        #pragma unroll
        for (int k = 0; k < 2; ++k)
            GLOAD_LDS(gt + (seg + k) * 1024 + l16, lq + 8192 + (seg + k) * 1024);
    };

    stage_fn(0, bb0);
    __syncthreads();
    int cur = 0;

    for (int r = 0; r < R; ++r) {
        if (r + 1 < R) stage_fn(cur ^ 1, bb0 + r + 1);   // T14: issue early

        const char* qbL = stageMem[cur];
        const char* qTL = stageMem[cur] + 8192;

        // ---- QK^T (t folded at k=100) ----
        f32x16 sacc = {};
        __builtin_amdgcn_s_setprio(1);
        #pragma unroll
        for (int kk = 0; kk < 7; ++kk) {
            f16x8 aq = *reinterpret_cast<const f16x8*>(qbL + kk * 1024 + l16);
            sacc = MFMA32(aq, cbF[kk], sacc);
        }
        __builtin_amdgcn_s_setprio(0);

        float sc[16];
        #pragma unroll
        for (int q16 = 0; q16 < 16; ++q16) sc[q16] = sacc[q16];

        // ---- per-half tile max + defer-max ----
        float t0 = fmaxf(sc[0], sc[1]),  t1 = fmaxf(sc[2], sc[3]);
        float t2 = fmaxf(sc[4], sc[5]),  t3 = fmaxf(sc[6], sc[7]);
        float t4 = fmaxf(sc[8], sc[9]),  t5 = fmaxf(sc[10], sc[11]);
        float t6 = fmaxf(sc[12], sc[13]), t7 = fmaxf(sc[14], sc[15]);
        t0 = fmaxf(t0, t1); t2 = fmaxf(t2, t3);
        t4 = fmaxf(t4, t5); t6 = fmaxf(t6, t7);
        float tm = fmaxf(fmaxf(t0, t2), fmaxf(t4, t6));
        mtrue = fmaxf(mtrue, tm);

        if (__any(tm > m + THR)) {
            float tmf = fmaxf(tm, __shfl_xor(tm, 32, 64));
            float mn = fmaxf(m, tmf);
            float scale = __expf(m - mn);
            U0 *= scale; U1 *= scale; U2 *= scale; U3 *= scale;
            m = mn;
        }

        #pragma unroll
        for (int q16 = 0; q16 < 16; ++q16) sc[q16] = __expf(sc[q16] - m);

        // ---- P -> PV B-operand ----
        unsigned int pk[8], pr[8];
        #pragma unroll
        for (int h2 = 0; h2 < 8; ++h2) {
            PkU u; u.h2[0] = (_Float16)sc[2 * h2]; u.h2[1] = (_Float16)sc[2 * h2 + 1];
            pk[h2] = u.u;
            pr[h2] = (unsigned int)__shfl_xor((int)pk[h2], 32, 64);
        }
        FragU f0, f1;
        f0.u[0] = hi ? pr[2] : pk[0];
        f0.u[1] = hi ? pr[3] : pk[1];
        f0.u[2] = hi ? pk[2] : pr[0];
        f0.u[3] = hi ? pk[3] : pr[1];
        f1.u[0] = hi ? pr[6] : pk[4];
        f1.u[1] = hi ? pr[7] : pk[5];
        f1.u[2] = hi ? pk[6] : pr[4];
        f1.u[3] = hi ? pk[7] : pr[5];

        // ---- PV (av reads: base + lane*16, conflict-free) ----
        __builtin_amdgcn_s_setprio(1);
        {
            f16x8 a0 = *reinterpret_cast<const f16x8*>(qTL + l16);
            f16x8 a1 = *reinterpret_cast<const f16x8*>(qTL + 1024 + l16);
            U0 = MFMA32(a0, f0.v, U0);
            U0 = MFMA32(a1, f1.v, U0);
        }
        {
            f16x8 a0 = *reinterpret_cast<const f16x8*>(qTL + 2048 + l16);
            f16x8 a1 = *reinterpret_cast<const f16x8*>(qTL + 3072 + l16);
            U1 = MFMA32(a0, f0.v, U1);
            U1 = MFMA32(a1, f1.v, U1);
        }
        {
            f16x8 a0 = *reinterpret_cast<const f16x8*>(qTL + 4096 + l16);
            f16x8 a1 = *reinterpret_cast<const f16x8*>(qTL + 5120 + l16);
            U2 = MFMA32(a0, f0.v, U2);
            U2 = MFMA32(a1, f1.v, U2);
        }
        {
            f16x8 a0 = *reinterpret_cast<const f16x8*>(qTL + 6144 + l16);
            f16x8 a1 = *reinterpret_cast<const f16x8*>(qTL + 7168 + l16);
            U3 = MFMA32(a0, f0.v, U3);
            U3 = MFMA32(a1, f1.v, U3);
        }
        __builtin_amdgcn_s_setprio(0);

        __syncthreads();            // drains this round's prefetch DMAs too
        cur ^= 1;
    }

    // ---- epilogue: per-wave partials to gmem ----
    mtrue = fmaxf(mtrue, __shfl_xor(mtrue, 32, 64));
    float ltmp = __shfl_xor(U3[0], 32, 64);     // d=100 ones-row -> l (hi=1, reg 0)
    float lfull = hi ? U3[0] : ltmp;

    int irow = iw0 + c31;
    if (hi == 0) {
        mb [(size_t)js * N_CTX + irow] = m;
        lb [(size_t)js * N_CTX + irow] = lfull;
        mtb[(size_t)js * N_CTX + irow] = mtrue;
    }
    _Float16* ub = Ub + (((size_t)js * 128 + it) * DIM) * 128 + w * 32 + c31;
    #pragma unroll
    for (int r = 0; r < 16; ++r) {
        int dl = (r & 3) + 8 * (r >> 2) + 4 * hi;
        ub[(size_t)dl * 128]        = (_Float16)U0[r];
        ub[(size_t)(32 + dl) * 128] = (_Float16)U1[r];
        ub[(size_t)(64 + dl) * 128] = (_Float16)U2[r];
        if (96 + dl < DIM) ub[(size_t)(96 + dl) * 128] = (_Float16)U3[r];
    }
}

// ---------------- cross-split combine + epilogue ----------------
template<int JS>
__global__ void combine(const _Float16* __restrict__ Ub, const float* __restrict__ mb,
                        const float* __restrict__ lb, const float* __restrict__ mtb,
                        const float* __restrict__ a, const float* __restrict__ ctx,
                        float* __restrict__ G, float* __restrict__ mfull)
{
    int tid = threadIdx.x;
    int i32 = tid & 31, seg = tid >> 5;
    int row = blockIdx.x * 32 + i32;
    int iblk = row >> 7, il = row & 127;

    float mw[JS];
    float M = -INFINITY;
    #pragma unroll
    for (int js = 0; js < JS; ++js) {
        mw[js] = mb[(size_t)js * N_CTX + row];
        M = fmaxf(M, mw[js]);
    }
    float ew[JS];
    float L = 0.f, Mt = -INFINITY;
    #pragma unroll
    for (int js = 0; js < JS; ++js) {
        ew[js] = __expf(mw[js] - M);
        L += lb[(size_t)js * N_CTX + row] * ew[js];
        Mt = fmaxf(Mt, mtb[(size_t)js * N_CTX + row]);
    }
    if (seg == 0) mfull[row] = a[row] + Mt;
    float invL = 1.f / L;
    for (int d = seg; d < DIM; d += 8) {
        float u = 0.f;
        #pragma unroll
        for (int js = 0; js < JS; ++js)
            u += (float)Ub[(((size_t)js * 128 + iblk) * DIM + d) * 128 + il] * ew[js];
        float ua = u * invL;
        float cv = ctx[(size_t)row * DIM + d];
        size_t base = (size_t)row * 400;
        G[base + d]       = cv;
        G[base + 100 + d] = ua;
        G[base + 200 + d] = ua * cv;
    }
}

// ---------------- b-softmax + h (coalesced accumulate) ----------------
__global__ void kernel_h(const float* __restrict__ mfull, const float* __restrict__ ctx,
                         float* __restrict__ hp) {
    __shared__ float sm[256];
    __shared__ float smh[8][104];
    int t = threadIdx.x;
    float v = -INFINITY;
    for (int i = t; i < N_CTX; i += 256) v = fmaxf(v, mfull[i]);
    sm[t] = v; __syncthreads();
    for (int s = 128; s > 0; s >>= 1) { if (t < s) sm[t] = fmaxf(sm[t], sm[t + s]); __syncthreads(); }
    float M = sm[0];
    __syncthreads();
    float z = 0.f;
    for (int i = t; i < N_CTX; i += 256) z += __expf(mfull[i] - M);
    sm[t] = z; __syncthreads();
    for (int s = 128; s > 0; s >>= 1) { if (t < s) sm[t] += sm[t + s]; __syncthreads(); }
    float Z = sm[0];
    __syncthreads();

    int rr = t >> 5, d32 = t & 31;
    int i0 = blockIdx.x * 64;
    float a0 = 0.f, a1 = 0.f, a2 = 0.f, a3 = 0.f;
    for (int g = 0; g < 8; ++g) {
        int row = i0 + g * 8 + rr;
        float bw = __expf(mfull[row] - M);
        const float* cr = ctx + (size_t)row * DIM;
        a0 += bw * cr[d32];
        a1 += bw * cr[d32 + 32];
        a2 += bw * cr[d32 + 64];
        if (d32 < 4) a3 += bw * cr[d32 + 96];
    }
    smh[rr][d32]      = a0;
    smh[rr][d32 + 32] = a1;
    smh[rr][d32 + 64] = a2;
    if (d32 < 4) smh[rr][d32 + 96] = a3;
    __syncthreads();
    if (t < DIM) {
        float s = 0.f;
        #pragma unroll
        for (int g = 0; g < 8; ++g) s += smh[g][t];
        hp[blockIdx.x * 128 + t] = s / Z;
    }
}

__global__ void kernel_hred(const float* __restrict__ hp, float* __restrict__ h) {
    __shared__ float sm[4][128];
    int t = threadIdx.x;
    int d = t & 127, rep = t >> 7;
    float s = 0.f;
    if (d < DIM) for (int b = 0; b < 64; ++b) s += hp[(rep * 64 + b) * 128 + d];
    sm[rep][d] = s;
    __syncthreads();
    if (rep == 0 && d < DIM) h[d] = sm[0][d] + sm[1][d] + sm[2][d] + sm[3][d];
}

__global__ void kernel_g4(const float* __restrict__ ctx, const float* __restrict__ h,
                          float* __restrict__ G) {
    int idx = blockIdx.x * 256 + threadIdx.x;
    if (idx >= N_CTX * DIM) return;
    int i = idx / DIM;
    int d = idx - i * DIM;
    G[(size_t)i * 400 + 300 + d] = ctx[idx] * h[d];
}

// ---------------- launcher ----------------
extern "C" void kernel_launch(void* const* d_in, const int* in_sizes, int n_in,
                              void* d_out, int out_size, void* d_ws, size_t ws_size,
                              hipStream_t stream) {
    const float* ctx = (const float*)d_in[0];
    const float* q   = (const float*)d_in[1];
    const float* ker = (const float*)d_in[2];
    float* G = (float*)d_out;

    char* ws = (char*)d_ws;
    unsigned short* qbS   = (unsigned short*)(ws);                 // 1,048,576
    unsigned short* qTS   = (unsigned short*)(ws + 1048576);       // 1,048,576
    unsigned short* cbH   = (unsigned short*)(ws + 2097152);       // 4,194,304
    float*          a     = (float*)(ws + 6291456);                // 65,536
    float*          mfull = (float*)(ws + 6356992);                // 65,536
    float*          hp    = (float*)(ws + 6422528);                // 131,072
    float*          h     = (float*)(ws + 6553600);                // 512
    const size_t fixed = 6554112;

    int JS = 8;
    if (fixed + 8ull * 3473408ull > ws_size) JS = 4;
    if (fixed + 4ull * 3473408ull > ws_size) JS = 2;

    _Float16* Ub  = (_Float16*)(ws + fixed);
    size_t ubB    = (size_t)JS * 3276800ull;
    float*    mb  = (float*)(ws + fixed + ubB);
    float*    lb  = (float*)(ws + fixed + ubB + (size_t)JS * 65536ull);
    float*    mtb = (float*)(ws + fixed + ubB + (size_t)JS * 131072ull);

    prep_all<<<dim3(208), dim3(256), 0, stream>>>(q, ctx, ker, qbS, qTS, cbH, a);
    attn_main<<<dim3(128, JS), dim3(256), 0, stream>>>(qbS, qTS, cbH, Ub, mb, lb, mtb);
    if (JS == 8)
        combine<8><<<dim3(512), dim3(256), 0, stream>>>(Ub, mb, lb, mtb, a, ctx, G, mfull);
    else if (JS == 4)
        combine<4><<<dim3(512), dim3(256), 0, stream>>>(Ub, mb, lb, mtb, a, ctx, G, mfull);
    else
        combine<2><<<dim3(512), dim3(256), 0, stream>>>(Ub, mb, lb, mtb, a, ctx, G, mfull);
    kernel_h<<<dim3(256), dim3(256), 0, stream>>>(mfull, ctx, hp);
    kernel_hred<<<dim3(1), dim3(512), 0, stream>>>(hp, h);
    kernel_g4<<<dim3(6400), dim3(256), 0, stream>>>(ctx, h, G);
}